// Round 2
// baseline (506.558 us; speedup 1.0000x reference)
//
#include <hip/hip_runtime.h>
#include <stdint.h>

typedef unsigned short u16;
typedef __bf16 bf16x8 __attribute__((ext_vector_type(8)));
typedef float  f32x4  __attribute__((ext_vector_type(4)));

#define N_TOK 8192
#define DIM   2048
#define NEXP  8
#define RPAD  18432   // >= 2*N_TOK + 8*255, rounded to 256 (BM=256 padding)
#define NCHUNK 32     // token chunks for slot assignment (256 tokens each)
#define GT    576     // gemm tiles: (RPAD/256) * (DIM/256) = 72*8

// ---- ws layout (bytes) ----
#define OFF_CNT   0                       // int[8]
#define OFF_HIST  1024                    // int[NCHUNK*8]
#define OFF_PRE   2048                    // int[NCHUNK*8]
#define OFF_RE    4096                    // int2[N_TOK]
#define OFF_RI    (OFF_RE + N_TOK * 8)    // int4[N_TOK]
#define OFF_RW    (OFF_RI + N_TOK * 16)   // float2[N_TOK]
#define OFF_TIDX  (OFF_RW + N_TOK * 8)    // int[NEXP*N_TOK]
#define OFF_XB    (OFF_TIDX + NEXP * N_TOK * 4)            // u16[N_TOK*DIM]
#define OFF_WT    (OFF_XB + (size_t)N_TOK * DIM * 2)       // u16[NEXP*DIM*DIM]
#define OFF_YP    (OFF_WT + (size_t)NEXP * DIM * DIM * 2)  // u16[RPAD*DIM]
// total ~243.8 MB

__device__ __forceinline__ unsigned f2bf(float f) {
    unsigned int u = __float_as_uint(f);
    u = (u + 0x7FFFu + ((u >> 16) & 1u)) >> 16;   // RNE; inputs finite
    return u;
}

__device__ __forceinline__ void gload16(const void* g, void* l) {
    __builtin_amdgcn_global_load_lds(
        (const __attribute__((address_space(1))) unsigned int*)g,
        (__attribute__((address_space(3))) unsigned int*)l,
        16, 0, 0);
}

// ---- gate: fused convert + fp64 logits, top-2. NO atomics. -------------
__global__ __launch_bounds__(256) void k_gate(
    const float* __restrict__ x, const float* __restrict__ Wg,
    int2* __restrict__ route_e, float2* __restrict__ route_w,
    u16* __restrict__ Xb) {
    int wave = threadIdx.x >> 6, lane = threadIdx.x & 63;
    int n = blockIdx.x * 4 + wave;
    const float* xr = x + (size_t)n * DIM;
    u16* xbr = Xb + (size_t)n * DIM;
    double acc[8] = {0, 0, 0, 0, 0, 0, 0, 0};
#pragma unroll
    for (int it = 0; it < 4; it++) {
        int c = it * 512 + lane * 8;
        float4 a = *(const float4*)(xr + c);
        float4 b = *(const float4*)(xr + c + 4);
        uint4 o;
        o.x = f2bf(a.x) | (f2bf(a.y) << 16);
        o.y = f2bf(a.z) | (f2bf(a.w) << 16);
        o.z = f2bf(b.x) | (f2bf(b.y) << 16);
        o.w = f2bf(b.z) | (f2bf(b.w) << 16);
        *(uint4*)(xbr + c) = o;
        float xv[8] = {a.x, a.y, a.z, a.w, b.x, b.y, b.z, b.w};
        const float4* wp = (const float4*)(Wg + (size_t)c * 8);
#pragma unroll
        for (int j = 0; j < 8; j++) {
            float4 w0 = wp[j * 2], w1 = wp[j * 2 + 1];
            double xd = (double)xv[j];
            acc[0] += xd * (double)w0.x;
            acc[1] += xd * (double)w0.y;
            acc[2] += xd * (double)w0.z;
            acc[3] += xd * (double)w0.w;
            acc[4] += xd * (double)w1.x;
            acc[5] += xd * (double)w1.y;
            acc[6] += xd * (double)w1.z;
            acc[7] += xd * (double)w1.w;
        }
    }
#pragma unroll
    for (int off = 32; off; off >>= 1)
#pragma unroll
        for (int e = 0; e < 8; e++) acc[e] += __shfl_xor(acc[e], off);
    if (lane == 0) {
        float v[8];
#pragma unroll
        for (int e = 0; e < 8; e++) v[e] = (float)acc[e];
        int e0 = 0; float v0 = v[0];
#pragma unroll
        for (int e = 1; e < 8; e++) if (v[e] > v0) { v0 = v[e]; e0 = e; }
        int e1 = -1; float v1 = -1e30f;
#pragma unroll
        for (int e = 0; e < 8; e++) if (e != e0 && v[e] > v1) { v1 = v[e]; e1 = e; }
        float ex = expf(v1 - v0);             // <= 1, stable
        route_e[n] = make_int2(e0, e1);
        route_w[n] = make_float2(1.0f / (1.0f + ex), ex / (1.0f + ex));
    }
}

// ---- hist: per-chunk expert histograms (32 blocks) ---------------------
__global__ __launch_bounds__(256) void k_hist(
    const int2* __restrict__ route_e, int* __restrict__ hist) {
    __shared__ int h[NEXP];
    int c = blockIdx.x, t = threadIdx.x;
    if (t < NEXP) h[t] = 0;
    __syncthreads();
    int2 re = route_e[c * 256 + t];
    atomicAdd(&h[re.x], 1);
    atomicAdd(&h[re.y], 1);
    __syncthreads();
    if (t < NEXP) hist[c * NEXP + t] = h[t];
}

// ---- scan: per-expert exclusive prefix over chunks (nano) --------------
__global__ void k_scan(const int* __restrict__ hist, int* __restrict__ pre,
                       int* __restrict__ cnt) {
    int e = threadIdx.x;
    if (e < NEXP) {
        int run = 0;
        for (int c = 0; c < NCHUNK; c++) { pre[c * NEXP + e] = run; run += hist[c * NEXP + e]; }
        cnt[e] = run;
    }
}

// ---- assign: ballot-ranked slot assignment (32 blocks) -----------------
__global__ __launch_bounds__(256) void k_assign(
    const int2* __restrict__ route_e, const int* __restrict__ pre,
    int4* __restrict__ route_i, int* __restrict__ tok_idx) {
    __shared__ int wc0[4][NEXP], wc1[4][NEXP];
    int c = blockIdx.x, t = threadIdx.x, wave = t >> 6, lane = t & 63;
    int n = c * 256 + t;
    int2 re = route_e[n];
    unsigned long long lt = ((unsigned long long)1 << lane) - 1;
    int r0 = 0, r1 = 0;
#pragma unroll
    for (int e = 0; e < NEXP; e++) {
        unsigned long long m0 = __ballot(re.x == e);
        unsigned long long m1 = __ballot(re.y == e);
        if (lane == 0) { wc0[wave][e] = __popcll(m0); wc1[wave][e] = __popcll(m1); }
        if (re.x == e) r0 = __popcll(m0 & lt);
        if (re.y == e) r1 = __popcll(m1 & lt);
    }
    __syncthreads();
    int h0tot = 0;   // total e0-instances of expert re.y in this chunk
#pragma unroll
    for (int w = 0; w < 4; w++) {
        if (w < wave) { r0 += wc0[w][re.x]; r1 += wc1[w][re.y]; }
        h0tot += wc0[w][re.y];
    }
    int p0 = pre[c * NEXP + re.x] + r0;
    int p1 = pre[c * NEXP + re.y] + h0tot + r1;
    route_i[n] = make_int4(re.x, re.y, p0, p1);
    tok_idx[re.x * N_TOK + p0] = n;
    tok_idx[re.y * N_TOK + p1] = n;
}

// ---- transpose We[e][k][n] fp32 -> Wt[e][n][k] bf16, 4 tiles/block -----
__global__ __launch_bounds__(256) void k_transpose_we(
    const float* __restrict__ We, u16* __restrict__ Wt) {
    __shared__ float t[64][65];
    int e = blockIdx.z, n0 = blockIdx.x * 64, k00 = blockIdx.y * 256;
    int tid = threadIdx.x;
    for (int kt = 0; kt < 4; kt++) {
        int k0 = k00 + kt * 64;
        const float* src = We + ((size_t)e * DIM + k0) * DIM + n0;
        if (kt) __syncthreads();
#pragma unroll
        for (int it = 0; it < 4; it++) {
            int item = it * 256 + tid;
            int r = item >> 4, c4 = (item & 15) * 4;
            float4 v = *(const float4*)(src + (size_t)r * DIM + c4);
            t[r][c4] = v.x; t[r][c4 + 1] = v.y; t[r][c4 + 2] = v.z; t[r][c4 + 3] = v.w;
        }
        __syncthreads();
        u16* dst = Wt + ((size_t)e * DIM + n0) * DIM + k0;
#pragma unroll
        for (int it = 0; it < 2; it++) {
            int item = it * 256 + tid;
            int nl = item >> 3, kc = (item & 7) * 8;
            unsigned m[8];
#pragma unroll
            for (int j = 0; j < 8; j++) m[j] = f2bf(t[kc + j][nl]);
            uint4 o;
            o.x = m[0] | (m[1] << 16); o.y = m[2] | (m[3] << 16);
            o.z = m[4] | (m[5] << 16); o.w = m[6] | (m[7] << 16);
            *(uint4*)(dst + (size_t)nl * DIM + kc) = o;
        }
    }
}

// ---- grouped gather-GEMM, 256x256 tile, BK=64, 8-wave 8-phase schedule -
// dbuf LDS 128 KiB; counted vmcnt with per-round consumption ages (T3+T4):
//   B-quadrant + A-first-round consumed at ph0, A-second-round at ph2.
//   issue B0,B1,A0,A2 @ph0 ; B2,B3,A1,A3 @ph1
//   drain prev A1,A3 @end-ph1 (vmcnt(8), age 4 phases)
//   drain B*,A0,A2   @end-ph3 (vmcnt(2), age 2.3-3.3 phases) -- never 0.
__global__ __launch_bounds__(512, 2) void k_moe_gemm(
    const u16* __restrict__ Xb, const u16* __restrict__ Wt,
    const float* __restrict__ be, const int* __restrict__ cnt,
    const int* __restrict__ tok_idx, u16* __restrict__ Yp) {
    extern __shared__ u16 lds[];   // [A0|A1|B0|B1] each 256*64 u16 = 32KB

    int base[NEXP]; int pb = 0;
#pragma unroll
    for (int i = 0; i < NEXP; i++) { base[i] = pb; pb += ((cnt[i] + 255) >> 8) << 8; }

    // XCD-aware bijective tile swizzle: 576 tiles, 8 XCDs, 72 tiles/XCD
    int f = blockIdx.x;
    f = (f & 7) * (GT / 8) + (f >> 3);
    int m0 = (f >> 3) << 8, n0 = (f & 7) << 8;
    if (m0 >= pb) return;
    int e = 0;
#pragma unroll
    for (int i = 1; i < NEXP; i++) if (m0 >= base[i]) e = i;

    int tid = threadIdx.x, wave = tid >> 6, lane = tid & 63;
    int q = lane >> 4, mr = lane & 15;
    int wr = (wave >> 2) << 7;   // 0 / 128
    int wc = (wave & 3) << 6;    // 0 / 64 / 128 / 192

    // per-lane pre-swizzled global staging pointers (4 64-row rounds each)
    const u16* pA[4]; const u16* pB[4];
#pragma unroll
    for (int j = 0; j < 4; j++) {
        int r = j * 64 + wave * 8 + (lane >> 3);
        int swz = ((lane & 7) ^ ((r >> 1) & 7)) << 3;
        int slot = m0 + r - base[e];
        int tok = tok_idx[e * N_TOK + slot] & (N_TOK - 1);   // pad rows masked
        pA[j] = Xb + (size_t)tok * DIM + swz;
        pB[j] = Wt + ((size_t)e * DIM + n0 + r) * DIM + swz;
    }

    u16* cA = lds;             u16* nA = lds + 16384;
    u16* cB = lds + 32768;     u16* nB = lds + 49152;
    int dofs = wave << 9;      // wave*8 rows * 64 elems

    f32x4 acc[8][4] = {};

    // ---- prologue: stage tile 0; issue order == steady-state order -----
    gload16(pB[0], cB + 0     + dofs);
    gload16(pB[1], cB + 4096  + dofs);
    gload16(pA[0], cA + 0     + dofs);
    gload16(pA[2], cA + 8192  + dofs);
    gload16(pB[2], cB + 8192  + dofs);
    gload16(pB[3], cB + 12288 + dofs);
    gload16(pA[1], cA + 4096  + dofs);
    gload16(pA[3], cA + 12288 + dofs);
    asm volatile("s_waitcnt vmcnt(2)" ::: "memory");   // A1,A3 stay in flight
    __builtin_amdgcn_s_barrier();
    __builtin_amdgcn_sched_barrier(0);

#pragma unroll 2
    for (int t = 0; t < 32; t++) {
        int koff = (t + 1 < 32 ? t + 1 : 31) << 6;   // last iter: harmless restage
        bf16x8 b[4][2];
#pragma unroll
        for (int p = 0; p < 4; p++) {
            // ---- ds reads for this phase (from cur buffers) ----
            if (p == 0) {
#pragma unroll
                for (int j = 0; j < 4; j++) {
                    int R = wc + j * 16 + mr, sw = (R >> 1) & 7;
                    b[j][0] = *(const bf16x8*)(cB + (R << 6) + (((0 + q) ^ sw) << 3));
                    b[j][1] = *(const bf16x8*)(cB + (R << 6) + (((4 + q) ^ sw) << 3));
                }
            }
            bf16x8 a[2][2];
#pragma unroll
            for (int i2 = 0; i2 < 2; i2++) {
                int R = wr + (p * 2 + i2) * 16 + mr, sw = (R >> 1) & 7;
                a[i2][0] = *(const bf16x8*)(cA + (R << 6) + (((0 + q) ^ sw) << 3));
                a[i2][1] = *(const bf16x8*)(cA + (R << 6) + (((4 + q) ^ sw) << 3));
            }
            // ---- stage next tile: all 8 issued across ph0/ph1 ----
            if (p == 0) { gload16(pB[0] + koff, nB + 0     + dofs);
                          gload16(pB[1] + koff, nB + 4096  + dofs);
                          gload16(pA[0] + koff, nA + 0     + dofs);
                          gload16(pA[2] + koff, nA + 8192  + dofs);
                          asm volatile("s_waitcnt lgkmcnt(8)" ::: "memory"); }
            if (p == 1) { gload16(pB[2] + koff, nB + 8192  + dofs);
                          gload16(pB[3] + koff, nB + 12288 + dofs);
                          gload16(pA[1] + koff, nA + 4096  + dofs);
                          gload16(pA[3] + koff, nA + 12288 + dofs); }
            __builtin_amdgcn_s_barrier();
            __builtin_amdgcn_sched_barrier(0);
            __builtin_amdgcn_s_setprio(1);
#pragma unroll
            for (int kh = 0; kh < 2; kh++)
#pragma unroll
                for (int i2 = 0; i2 < 2; i2++)
#pragma unroll
                    for (int j = 0; j < 4; j++)
                        acc[p * 2 + i2][j] = __builtin_amdgcn_mfma_f32_16x16x32_bf16(
                            a[i2][kh], b[j][kh], acc[p * 2 + i2][j], 0, 0, 0);
            __builtin_amdgcn_s_setprio(0);
            // counted waits (ledger: 2 in flight at iter start, +4 ph0, +4 ph1):
            // end ph1: 10 outstanding -> drain prev-tile A1,A3 (oldest 2).
            // end ph3: 8 outstanding  -> drain B0..B3,A0,A2; keep A1,A3.
            if (p == 1) asm volatile("s_waitcnt vmcnt(8)" ::: "memory");
            if (p == 3) asm volatile("s_waitcnt vmcnt(2)" ::: "memory");
            __builtin_amdgcn_s_barrier();
            __builtin_amdgcn_sched_barrier(0);
        }
        u16* tp;
        tp = cA; cA = nA; nA = tp;
        tp = cB; cB = nB; nB = tp;
    }
    asm volatile("s_waitcnt vmcnt(0)" ::: "memory");

    // ---- epilogue: bias + bf16 store ----------------------------------
    float bev[4];
#pragma unroll
    for (int j = 0; j < 4; j++) bev[j] = be[e * DIM + n0 + wc + j * 16 + mr];
#pragma unroll
    for (int i = 0; i < 8; i++) {
#pragma unroll
        for (int r = 0; r < 4; r++) {
            int row = wr + i * 16 + q * 4 + r;
            u16* yrow = Yp + (size_t)(m0 + row) * DIM + n0 + wc + mr;
#pragma unroll
            for (int j = 0; j < 4; j++)
                yrow[j * 16] = (u16)f2bf(acc[i][j][r] + bev[j]);
        }
    }
}

// ---- combine: out[n] = w0*Y[r0] + w1*Y[r1] -----------------------------
__global__ __launch_bounds__(256) void k_combine(
    const u16* __restrict__ Yp, const int* __restrict__ cnt,
    const int4* __restrict__ route_i, const float2* __restrict__ route_w,
    float* __restrict__ out) {
    int base[NEXP]; int pb = 0;
#pragma unroll
    for (int i = 0; i < NEXP; i++) { base[i] = pb; pb += ((cnt[i] + 255) >> 8) << 8; }
    int n = blockIdx.x, tid = threadIdx.x;
    int4 ri = route_i[n]; float2 w = route_w[n];
    size_t r0 = (size_t)base[ri.x] + ri.z;
    size_t r1 = (size_t)base[ri.y] + ri.w;
    uint4 ya = ((const uint4*)(Yp + r0 * DIM))[tid];
    uint4 yb = ((const uint4*)(Yp + r1 * DIM))[tid];
    float4 o0, o1;
    unsigned a, b;
    a = ya.x; b = yb.x;
    o0.x = w.x * __uint_as_float(a << 16) + w.y * __uint_as_float(b << 16);
    o0.y = w.x * __uint_as_float(a & 0xffff0000u) + w.y * __uint_as_float(b & 0xffff0000u);
    a = ya.y; b = yb.y;
    o0.z = w.x * __uint_as_float(a << 16) + w.y * __uint_as_float(b << 16);
    o0.w = w.x * __uint_as_float(a & 0xffff0000u) + w.y * __uint_as_float(b & 0xffff0000u);
    a = ya.z; b = yb.z;
    o1.x = w.x * __uint_as_float(a << 16) + w.y * __uint_as_float(b << 16);
    o1.y = w.x * __uint_as_float(a & 0xffff0000u) + w.y * __uint_as_float(b & 0xffff0000u);
    a = ya.w; b = yb.w;
    o1.z = w.x * __uint_as_float(a << 16) + w.y * __uint_as_float(b << 16);
    o1.w = w.x * __uint_as_float(a & 0xffff0000u) + w.y * __uint_as_float(b & 0xffff0000u);
    float4* op = (float4*)(out + (size_t)n * DIM) + tid * 2;
    op[0] = o0; op[1] = o1;
}

extern "C" void kernel_launch(void* const* d_in, const int* in_sizes, int n_in,
                              void* d_out, int out_size, void* d_ws, size_t ws_size,
                              hipStream_t stream) {
    const float* x  = (const float*)d_in[0];   // [N, D]
    const float* Wg = (const float*)d_in[1];   // [D, E]
    const float* We = (const float*)d_in[2];   // [E, D, D]
    const float* be = (const float*)d_in[3];   // [E, D]
    float* out = (float*)d_out;                // [N, D] fp32
    char* ws = (char*)d_ws;
    int*    cnt     = (int*)(ws + OFF_CNT);
    int*    hist    = (int*)(ws + OFF_HIST);
    int*    pre     = (int*)(ws + OFF_PRE);
    int2*   route_e = (int2*)(ws + OFF_RE);
    int4*   route_i = (int4*)(ws + OFF_RI);
    float2* route_w = (float2*)(ws + OFF_RW);
    int*    tok_idx = (int*)(ws + OFF_TIDX);
    u16*    Xb      = (u16*)(ws + OFF_XB);
    u16*    Wt      = (u16*)(ws + OFF_WT);
    u16*    Yp      = (u16*)(ws + OFF_YP);

    static int g_attr_done = 0;
    if (!g_attr_done) {
        (void)hipFuncSetAttribute((const void*)k_moe_gemm,
                                  hipFuncAttributeMaxDynamicSharedMemorySize,
                                  131072);
        g_attr_done = 1;
    }

    k_gate<<<N_TOK / 4, 256, 0, stream>>>(x, Wg, route_e, route_w, Xb);
    k_hist<<<NCHUNK, 256, 0, stream>>>(route_e, hist);
    k_scan<<<1, 64, 0, stream>>>(hist, pre, cnt);
    k_assign<<<NCHUNK, 256, 0, stream>>>(route_e, pre, route_i, tok_idx);
    k_transpose_we<<<dim3(DIM / 64, DIM / 256, NEXP), 256, 0, stream>>>(We, Wt);
    k_moe_gemm<<<dim3(GT), 512, 131072, stream>>>(Xb, Wt, be, cnt, tok_idx, Yp);
    k_combine<<<N_TOK, 256, 0, stream>>>(Yp, cnt, route_i, route_w, out);
}

// Round 3
// 499.470 us; speedup vs baseline: 1.0142x; 1.0142x over previous
//
#include <hip/hip_runtime.h>
#include <stdint.h>

typedef unsigned short u16;
typedef __bf16 bf16x8 __attribute__((ext_vector_type(8)));
typedef float  f32x4  __attribute__((ext_vector_type(4)));

#define N_TOK 8192
#define DIM   2048
#define NEXP  8
#define RPAD  18432   // >= 2*N_TOK + 8*255, rounded to 256 (BM=256 padding)
#define NCHUNK 32     // token chunks for slot assignment (256 tokens each)
#define GT    576     // gemm tiles: (RPAD/256) * (DIM/256) = 72*8

// ---- ws layout (bytes) ----
#define OFF_CNT   0                       // int[8]
#define OFF_HIST  1024                    // int[NCHUNK*8]
#define OFF_PRE   2048                    // int[NCHUNK*8]
#define OFF_RE    4096                    // int2[N_TOK]
#define OFF_RI    (OFF_RE + N_TOK * 8)    // int4[N_TOK]
#define OFF_RW    (OFF_RI + N_TOK * 16)   // float2[N_TOK]
#define OFF_TIDX  (OFF_RW + N_TOK * 8)    // int[NEXP*N_TOK]
#define OFF_XB    (OFF_TIDX + NEXP * N_TOK * 4)            // u16[N_TOK*DIM]
#define OFF_WT    (OFF_XB + (size_t)N_TOK * DIM * 2)       // u16[NEXP*DIM*DIM]
#define OFF_YP    (OFF_WT + (size_t)NEXP * DIM * DIM * 2)  // u16[RPAD*DIM]
// total ~243.8 MB

__device__ __forceinline__ unsigned f2bf(float f) {
    unsigned int u = __float_as_uint(f);
    u = (u + 0x7FFFu + ((u >> 16) & 1u)) >> 16;   // RNE; inputs finite
    return u;
}

__device__ __forceinline__ void gload16(const void* g, void* l) {
    __builtin_amdgcn_global_load_lds(
        (const __attribute__((address_space(1))) unsigned int*)g,
        (__attribute__((address_space(3))) unsigned int*)l,
        16, 0, 0);
}

// ---- gate: fused convert + fp64 logits, top-2. NO atomics. -------------
__global__ __launch_bounds__(256) void k_gate(
    const float* __restrict__ x, const float* __restrict__ Wg,
    int2* __restrict__ route_e, float2* __restrict__ route_w,
    u16* __restrict__ Xb) {
    int wave = threadIdx.x >> 6, lane = threadIdx.x & 63;
    int n = blockIdx.x * 4 + wave;
    const float* xr = x + (size_t)n * DIM;
    u16* xbr = Xb + (size_t)n * DIM;
    double acc[8] = {0, 0, 0, 0, 0, 0, 0, 0};
#pragma unroll
    for (int it = 0; it < 4; it++) {
        int c = it * 512 + lane * 8;
        float4 a = *(const float4*)(xr + c);
        float4 b = *(const float4*)(xr + c + 4);
        uint4 o;
        o.x = f2bf(a.x) | (f2bf(a.y) << 16);
        o.y = f2bf(a.z) | (f2bf(a.w) << 16);
        o.z = f2bf(b.x) | (f2bf(b.y) << 16);
        o.w = f2bf(b.z) | (f2bf(b.w) << 16);
        *(uint4*)(xbr + c) = o;
        float xv[8] = {a.x, a.y, a.z, a.w, b.x, b.y, b.z, b.w};
        const float4* wp = (const float4*)(Wg + (size_t)c * 8);
#pragma unroll
        for (int j = 0; j < 8; j++) {
            float4 w0 = wp[j * 2], w1 = wp[j * 2 + 1];
            double xd = (double)xv[j];
            acc[0] += xd * (double)w0.x;
            acc[1] += xd * (double)w0.y;
            acc[2] += xd * (double)w0.z;
            acc[3] += xd * (double)w0.w;
            acc[4] += xd * (double)w1.x;
            acc[5] += xd * (double)w1.y;
            acc[6] += xd * (double)w1.z;
            acc[7] += xd * (double)w1.w;
        }
    }
#pragma unroll
    for (int off = 32; off; off >>= 1)
#pragma unroll
        for (int e = 0; e < 8; e++) acc[e] += __shfl_xor(acc[e], off);
    if (lane == 0) {
        float v[8];
#pragma unroll
        for (int e = 0; e < 8; e++) v[e] = (float)acc[e];
        int e0 = 0; float v0 = v[0];
#pragma unroll
        for (int e = 1; e < 8; e++) if (v[e] > v0) { v0 = v[e]; e0 = e; }
        int e1 = -1; float v1 = -1e30f;
#pragma unroll
        for (int e = 0; e < 8; e++) if (e != e0 && v[e] > v1) { v1 = v[e]; e1 = e; }
        float ex = expf(v1 - v0);             // <= 1, stable
        route_e[n] = make_int2(e0, e1);
        route_w[n] = make_float2(1.0f / (1.0f + ex), ex / (1.0f + ex));
    }
}

// ---- hist: per-chunk expert histograms (32 blocks) ---------------------
__global__ __launch_bounds__(256) void k_hist(
    const int2* __restrict__ route_e, int* __restrict__ hist) {
    __shared__ int h[NEXP];
    int c = blockIdx.x, t = threadIdx.x;
    if (t < NEXP) h[t] = 0;
    __syncthreads();
    int2 re = route_e[c * 256 + t];
    atomicAdd(&h[re.x], 1);
    atomicAdd(&h[re.y], 1);
    __syncthreads();
    if (t < NEXP) hist[c * NEXP + t] = h[t];
}

// ---- scan: per-expert exclusive prefix over chunks (nano) --------------
__global__ void k_scan(const int* __restrict__ hist, int* __restrict__ pre,
                       int* __restrict__ cnt) {
    int e = threadIdx.x;
    if (e < NEXP) {
        int run = 0;
        for (int c = 0; c < NCHUNK; c++) { pre[c * NEXP + e] = run; run += hist[c * NEXP + e]; }
        cnt[e] = run;
    }
}

// ---- assign: ballot-ranked slot assignment (32 blocks) -----------------
__global__ __launch_bounds__(256) void k_assign(
    const int2* __restrict__ route_e, const int* __restrict__ pre,
    int4* __restrict__ route_i, int* __restrict__ tok_idx) {
    __shared__ int wc0[4][NEXP], wc1[4][NEXP];
    int c = blockIdx.x, t = threadIdx.x, wave = t >> 6, lane = t & 63;
    int n = c * 256 + t;
    int2 re = route_e[n];
    unsigned long long lt = ((unsigned long long)1 << lane) - 1;
    int r0 = 0, r1 = 0;
#pragma unroll
    for (int e = 0; e < NEXP; e++) {
        unsigned long long m0 = __ballot(re.x == e);
        unsigned long long m1 = __ballot(re.y == e);
        if (lane == 0) { wc0[wave][e] = __popcll(m0); wc1[wave][e] = __popcll(m1); }
        if (re.x == e) r0 = __popcll(m0 & lt);
        if (re.y == e) r1 = __popcll(m1 & lt);
    }
    __syncthreads();
    int h0tot = 0;   // total e0-instances of expert re.y in this chunk
#pragma unroll
    for (int w = 0; w < 4; w++) {
        if (w < wave) { r0 += wc0[w][re.x]; r1 += wc1[w][re.y]; }
        h0tot += wc0[w][re.y];
    }
    int p0 = pre[c * NEXP + re.x] + r0;
    int p1 = pre[c * NEXP + re.y] + h0tot + r1;
    route_i[n] = make_int4(re.x, re.y, p0, p1);
    tok_idx[re.x * N_TOK + p0] = n;
    tok_idx[re.y * N_TOK + p1] = n;
}

// ---- transpose We[e][k][n] fp32 -> Wt[e][n][k] bf16, 4 tiles/block -----
__global__ __launch_bounds__(256) void k_transpose_we(
    const float* __restrict__ We, u16* __restrict__ Wt) {
    __shared__ float t[64][65];
    int e = blockIdx.z, n0 = blockIdx.x * 64, k00 = blockIdx.y * 256;
    int tid = threadIdx.x;
    for (int kt = 0; kt < 4; kt++) {
        int k0 = k00 + kt * 64;
        const float* src = We + ((size_t)e * DIM + k0) * DIM + n0;
        if (kt) __syncthreads();
#pragma unroll
        for (int it = 0; it < 4; it++) {
            int item = it * 256 + tid;
            int r = item >> 4, c4 = (item & 15) * 4;
            float4 v = *(const float4*)(src + (size_t)r * DIM + c4);
            t[r][c4] = v.x; t[r][c4 + 1] = v.y; t[r][c4 + 2] = v.z; t[r][c4 + 3] = v.w;
        }
        __syncthreads();
        u16* dst = Wt + ((size_t)e * DIM + n0) * DIM + k0;
#pragma unroll
        for (int it = 0; it < 2; it++) {
            int item = it * 256 + tid;
            int nl = item >> 3, kc = (item & 7) * 8;
            unsigned m[8];
#pragma unroll
            for (int j = 0; j < 8; j++) m[j] = f2bf(t[kc + j][nl]);
            uint4 o;
            o.x = m[0] | (m[1] << 16); o.y = m[2] | (m[3] << 16);
            o.z = m[4] | (m[5] << 16); o.w = m[6] | (m[7] << 16);
            *(uint4*)(dst + (size_t)nl * DIM + kc) = o;
        }
    }
}

// ---- grouped gather-GEMM, 256x256 tile, BK=64, 8 waves -----------------
// Full dbuf => NO intra-tile hazards => only 2 barriers per K-tile:
//   Bmid  (after vmcnt(8)): publishes prev-issued A-late rounds (A1,A3)
//   Bend  (after vmcnt(2)): publishes next tile's B + A-early; keeps the
//                           next tile's A1,A3 in flight across the barrier.
// Between barriers waves free-run; compiler's fine-grained lgkmcnt
// interleaves ds_read with MFMA; wave jitter de-bursts the LDS pipe.
__global__ __launch_bounds__(512, 2) void k_moe_gemm(
    const u16* __restrict__ Xb, const u16* __restrict__ Wt,
    const float* __restrict__ be, const int* __restrict__ cnt,
    const int* __restrict__ tok_idx, u16* __restrict__ Yp) {
    extern __shared__ u16 lds[];   // [A0|A1|B0|B1] each 256*64 u16 = 32KB

    int base[NEXP]; int pb = 0;
#pragma unroll
    for (int i = 0; i < NEXP; i++) { base[i] = pb; pb += ((cnt[i] + 255) >> 8) << 8; }

    // XCD-aware bijective tile swizzle: 576 tiles, 8 XCDs, 72 tiles/XCD
    int f = blockIdx.x;
    f = (f & 7) * (GT / 8) + (f >> 3);
    int m0 = (f >> 3) << 8, n0 = (f & 7) << 8;
    if (m0 >= pb) return;
    int e = 0;
#pragma unroll
    for (int i = 1; i < NEXP; i++) if (m0 >= base[i]) e = i;

    int tid = threadIdx.x, wave = tid >> 6, lane = tid & 63;
    int q = lane >> 4, mr = lane & 15;
    int wr = (wave >> 2) << 7;   // 0 / 128
    int wc = (wave & 3) << 6;    // 0 / 64 / 128 / 192

    // per-lane pre-swizzled global staging pointers (4 64-row rounds each)
    const u16* pA[4]; const u16* pB[4];
#pragma unroll
    for (int j = 0; j < 4; j++) {
        int r = j * 64 + wave * 8 + (lane >> 3);
        int swz = ((lane & 7) ^ ((r >> 1) & 7)) << 3;
        int slot = m0 + r - base[e];
        int tok = tok_idx[e * N_TOK + slot] & (N_TOK - 1);   // pad rows masked
        pA[j] = Xb + (size_t)tok * DIM + swz;
        pB[j] = Wt + ((size_t)e * DIM + n0 + r) * DIM + swz;
    }

    u16* cA = lds;             u16* nA = lds + 16384;
    u16* cB = lds + 32768;     u16* nB = lds + 49152;
    int dofs = wave << 9;      // wave*8 rows * 64 elems

    f32x4 acc[8][4] = {};

    // ---- prologue: stage tile 0; issue order == steady-state order -----
    gload16(pB[0], cB + 0     + dofs);
    gload16(pB[1], cB + 4096  + dofs);
    gload16(pA[0], cA + 0     + dofs);
    gload16(pA[2], cA + 8192  + dofs);
    gload16(pB[2], cB + 8192  + dofs);
    gload16(pB[3], cB + 12288 + dofs);
    gload16(pA[1], cA + 4096  + dofs);
    gload16(pA[3], cA + 12288 + dofs);
    asm volatile("s_waitcnt vmcnt(2)" ::: "memory");   // A1,A3 stay in flight
    __builtin_amdgcn_s_barrier();
    __builtin_amdgcn_sched_barrier(0);

#pragma unroll 2
    for (int t = 0; t < 32; t++) {
        int koff = (t + 1 < 32 ? t + 1 : 31) << 6;   // last iter: harmless restage
        // ======== half 1: B + A-early (acc rows 0..3), stage t+1 ========
        gload16(pB[0] + koff, nB + 0     + dofs);
        gload16(pB[1] + koff, nB + 4096  + dofs);
        gload16(pA[0] + koff, nA + 0     + dofs);
        gload16(pA[2] + koff, nA + 8192  + dofs);
        bf16x8 b[4][2];
#pragma unroll
        for (int j = 0; j < 4; j++) {
            int R = wc + j * 16 + mr, sw = (R >> 1) & 7;
            b[j][0] = *(const bf16x8*)(cB + (R << 6) + (((0 + q) ^ sw) << 3));
            b[j][1] = *(const bf16x8*)(cB + (R << 6) + (((4 + q) ^ sw) << 3));
        }
        {
            bf16x8 a[2][2];
#pragma unroll
            for (int i2 = 0; i2 < 2; i2++) {
                int R = wr + i2 * 16 + mr, sw = (R >> 1) & 7;
                a[i2][0] = *(const bf16x8*)(cA + (R << 6) + (((0 + q) ^ sw) << 3));
                a[i2][1] = *(const bf16x8*)(cA + (R << 6) + (((4 + q) ^ sw) << 3));
            }
            __builtin_amdgcn_s_setprio(1);
#pragma unroll
            for (int kh = 0; kh < 2; kh++)
#pragma unroll
                for (int i2 = 0; i2 < 2; i2++)
#pragma unroll
                    for (int j = 0; j < 4; j++)
                        acc[i2][j] = __builtin_amdgcn_mfma_f32_16x16x32_bf16(
                            a[i2][kh], b[j][kh], acc[i2][j], 0, 0, 0);
            __builtin_amdgcn_s_setprio(0);
        }
        gload16(pB[2] + koff, nB + 8192  + dofs);
        gload16(pB[3] + koff, nB + 12288 + dofs);
        gload16(pA[1] + koff, nA + 4096  + dofs);
        gload16(pA[3] + koff, nA + 12288 + dofs);
        {
            bf16x8 a[2][2];
#pragma unroll
            for (int i2 = 0; i2 < 2; i2++) {
                int R = wr + 32 + i2 * 16 + mr, sw = (R >> 1) & 7;
                a[i2][0] = *(const bf16x8*)(cA + (R << 6) + (((0 + q) ^ sw) << 3));
                a[i2][1] = *(const bf16x8*)(cA + (R << 6) + (((4 + q) ^ sw) << 3));
            }
            __builtin_amdgcn_s_setprio(1);
#pragma unroll
            for (int kh = 0; kh < 2; kh++)
#pragma unroll
                for (int i2 = 0; i2 < 2; i2++)
#pragma unroll
                    for (int j = 0; j < 4; j++)
                        acc[2 + i2][j] = __builtin_amdgcn_mfma_f32_16x16x32_bf16(
                            a[i2][kh], b[j][kh], acc[2 + i2][j], 0, 0, 0);
            __builtin_amdgcn_s_setprio(0);
        }
        // ledger: carried-in 2 (A1,A3 of t) + 8 issued => drain the 2 oldest
        asm volatile("s_waitcnt vmcnt(8)" ::: "memory");
        __builtin_amdgcn_sched_barrier(0);
        __builtin_amdgcn_s_barrier();            // Bmid: A-late of t valid
        __builtin_amdgcn_sched_barrier(0);
        // ======== half 2: A-late (acc rows 4..7) ========
        {
            bf16x8 a[2][2];
#pragma unroll
            for (int i2 = 0; i2 < 2; i2++) {
                int R = wr + 64 + i2 * 16 + mr, sw = (R >> 1) & 7;
                a[i2][0] = *(const bf16x8*)(cA + (R << 6) + (((0 + q) ^ sw) << 3));
                a[i2][1] = *(const bf16x8*)(cA + (R << 6) + (((4 + q) ^ sw) << 3));
            }
            __builtin_amdgcn_s_setprio(1);
#pragma unroll
            for (int kh = 0; kh < 2; kh++)
#pragma unroll
                for (int i2 = 0; i2 < 2; i2++)
#pragma unroll
                    for (int j = 0; j < 4; j++)
                        acc[4 + i2][j] = __builtin_amdgcn_mfma_f32_16x16x32_bf16(
                            a[i2][kh], b[j][kh], acc[4 + i2][j], 0, 0, 0);
            __builtin_amdgcn_s_setprio(0);
        }
        {
            bf16x8 a[2][2];
#pragma unroll
            for (int i2 = 0; i2 < 2; i2++) {
                int R = wr + 96 + i2 * 16 + mr, sw = (R >> 1) & 7;
                a[i2][0] = *(const bf16x8*)(cA + (R << 6) + (((0 + q) ^ sw) << 3));
                a[i2][1] = *(const bf16x8*)(cA + (R << 6) + (((4 + q) ^ sw) << 3));
            }
            __builtin_amdgcn_s_setprio(1);
#pragma unroll
            for (int kh = 0; kh < 2; kh++)
#pragma unroll
                for (int i2 = 0; i2 < 2; i2++)
#pragma unroll
                    for (int j = 0; j < 4; j++)
                        acc[6 + i2][j] = __builtin_amdgcn_mfma_f32_16x16x32_bf16(
                            a[i2][kh], b[j][kh], acc[6 + i2][j], 0, 0, 0);
            __builtin_amdgcn_s_setprio(0);
        }
        // keep next tile's A1,A3 in flight across the tile barrier
        asm volatile("s_waitcnt vmcnt(2)" ::: "memory");
        __builtin_amdgcn_sched_barrier(0);
        __builtin_amdgcn_s_barrier();            // Bend: B,A-early of t+1 valid
        __builtin_amdgcn_sched_barrier(0);
        u16* tp;
        tp = cA; cA = nA; nA = tp;
        tp = cB; cB = nB; nB = tp;
    }
    asm volatile("s_waitcnt vmcnt(0)" ::: "memory");

    // ---- epilogue: bias + bf16 store ----------------------------------
    float bev[4];
#pragma unroll
    for (int j = 0; j < 4; j++) bev[j] = be[e * DIM + n0 + wc + j * 16 + mr];
#pragma unroll
    for (int i = 0; i < 8; i++) {
#pragma unroll
        for (int r = 0; r < 4; r++) {
            int row = wr + i * 16 + q * 4 + r;
            u16* yrow = Yp + (size_t)(m0 + row) * DIM + n0 + wc + mr;
#pragma unroll
            for (int j = 0; j < 4; j++)
                yrow[j * 16] = (u16)f2bf(acc[i][j][r] + bev[j]);
        }
    }
}

// ---- combine: out[n] = w0*Y[r0] + w1*Y[r1] -----------------------------
__global__ __launch_bounds__(256) void k_combine(
    const u16* __restrict__ Yp, const int* __restrict__ cnt,
    const int4* __restrict__ route_i, const float2* __restrict__ route_w,
    float* __restrict__ out) {
    int base[NEXP]; int pb = 0;
#pragma unroll
    for (int i = 0; i < NEXP; i++) { base[i] = pb; pb += ((cnt[i] + 255) >> 8) << 8; }
    int n = blockIdx.x, tid = threadIdx.x;
    int4 ri = route_i[n]; float2 w = route_w[n];
    size_t r0 = (size_t)base[ri.x] + ri.z;
    size_t r1 = (size_t)base[ri.y] + ri.w;
    uint4 ya = ((const uint4*)(Yp + r0 * DIM))[tid];
    uint4 yb = ((const uint4*)(Yp + r1 * DIM))[tid];
    float4 o0, o1;
    unsigned a, b;
    a = ya.x; b = yb.x;
    o0.x = w.x * __uint_as_float(a << 16) + w.y * __uint_as_float(b << 16);
    o0.y = w.x * __uint_as_float(a & 0xffff0000u) + w.y * __uint_as_float(b & 0xffff0000u);
    a = ya.y; b = yb.y;
    o0.z = w.x * __uint_as_float(a << 16) + w.y * __uint_as_float(b << 16);
    o0.w = w.x * __uint_as_float(a & 0xffff0000u) + w.y * __uint_as_float(b & 0xffff0000u);
    a = ya.z; b = yb.z;
    o1.x = w.x * __uint_as_float(a << 16) + w.y * __uint_as_float(b << 16);
    o1.y = w.x * __uint_as_float(a & 0xffff0000u) + w.y * __uint_as_float(b & 0xffff0000u);
    a = ya.w; b = yb.w;
    o1.z = w.x * __uint_as_float(a << 16) + w.y * __uint_as_float(b << 16);
    o1.w = w.x * __uint_as_float(a & 0xffff0000u) + w.y * __uint_as_float(b & 0xffff0000u);
    float4* op = (float4*)(out + (size_t)n * DIM) + tid * 2;
    op[0] = o0; op[1] = o1;
}

extern "C" void kernel_launch(void* const* d_in, const int* in_sizes, int n_in,
                              void* d_out, int out_size, void* d_ws, size_t ws_size,
                              hipStream_t stream) {
    const float* x  = (const float*)d_in[0];   // [N, D]
    const float* Wg = (const float*)d_in[1];   // [D, E]
    const float* We = (const float*)d_in[2];   // [E, D, D]
    const float* be = (const float*)d_in[3];   // [E, D]
    float* out = (float*)d_out;                // [N, D] fp32
    char* ws = (char*)d_ws;
    int*    cnt     = (int*)(ws + OFF_CNT);
    int*    hist    = (int*)(ws + OFF_HIST);
    int*    pre     = (int*)(ws + OFF_PRE);
    int2*   route_e = (int2*)(ws + OFF_RE);
    int4*   route_i = (int4*)(ws + OFF_RI);
    float2* route_w = (float2*)(ws + OFF_RW);
    int*    tok_idx = (int*)(ws + OFF_TIDX);
    u16*    Xb      = (u16*)(ws + OFF_XB);
    u16*    Wt      = (u16*)(ws + OFF_WT);
    u16*    Yp      = (u16*)(ws + OFF_YP);

    static int g_attr_done = 0;
    if (!g_attr_done) {
        (void)hipFuncSetAttribute((const void*)k_moe_gemm,
                                  hipFuncAttributeMaxDynamicSharedMemorySize,
                                  131072);
        g_attr_done = 1;
    }

    k_gate<<<N_TOK / 4, 256, 0, stream>>>(x, Wg, route_e, route_w, Xb);
    k_hist<<<NCHUNK, 256, 0, stream>>>(route_e, hist);
    k_scan<<<1, 64, 0, stream>>>(hist, pre, cnt);
    k_assign<<<NCHUNK, 256, 0, stream>>>(route_e, pre, route_i, tok_idx);
    k_transpose_we<<<dim3(DIM / 64, DIM / 256, NEXP), 256, 0, stream>>>(We, Wt);
    k_moe_gemm<<<dim3(GT), 512, 131072, stream>>>(Xb, Wt, be, cnt, tok_idx, Yp);
    k_combine<<<N_TOK, 256, 0, stream>>>(Yp, cnt, route_i, route_w, out);
}

// Round 4
// 483.426 us; speedup vs baseline: 1.0478x; 1.0332x over previous
//
#include <hip/hip_runtime.h>
#include <stdint.h>

typedef unsigned short u16;
typedef __bf16 bf16x8 __attribute__((ext_vector_type(8)));
typedef float  f32x4  __attribute__((ext_vector_type(4)));

#define N_TOK 8192
#define DIM   2048
#define NEXP  8
#define RPAD  18432   // >= 2*N_TOK + 8*255, rounded to 256 (BM=256 padding)
#define NCHUNK 32     // token chunks for slot assignment (256 tokens each)
#define NFULL 512     // full-tile blocks (m-tiles 0..63, all n) -> exactly 2 rounds
#define NTAIL 64      // max overflow tiles (m-tiles 64..71), each split-K x8

// ---- ws layout (bytes) ----
#define OFF_CNT   0                       // int[8]
#define OFF_HIST  1024                    // int[NCHUNK*8]
#define OFF_PRE   2048                    // int[NCHUNK*8]
#define OFF_RE    4096                    // int2[N_TOK]
#define OFF_RI    (OFF_RE + N_TOK * 8)    // int4[N_TOK]
#define OFF_RW    (OFF_RI + N_TOK * 16)   // float2[N_TOK]
#define OFF_TIDX  (OFF_RW + N_TOK * 8)    // int[NEXP*N_TOK]
#define OFF_XB    (OFF_TIDX + NEXP * N_TOK * 4)            // u16[N_TOK*DIM]
#define OFF_WT    (OFF_XB + (size_t)N_TOK * DIM * 2)       // u16[NEXP*DIM*DIM]
#define OFF_YP    (OFF_WT + (size_t)NEXP * DIM * DIM * 2)  // u16[RPAD*DIM]
#define OFF_YS    (OFF_YP + (size_t)RPAD * DIM * 2)        // float[NTAIL*8*256*256] fp32 split-K partials
// total ~371.8 MB

__device__ __forceinline__ unsigned f2bf(float f) {
    unsigned int u = __float_as_uint(f);
    u = (u + 0x7FFFu + ((u >> 16) & 1u)) >> 16;   // RNE; inputs finite
    return u;
}

__device__ __forceinline__ void gload16(const void* g, void* l) {
    __builtin_amdgcn_global_load_lds(
        (const __attribute__((address_space(1))) unsigned int*)g,
        (__attribute__((address_space(3))) unsigned int*)l,
        16, 0, 0);
}

// ---- gate: fused convert + fp64 logits, top-2. NO atomics. -------------
__global__ __launch_bounds__(256) void k_gate(
    const float* __restrict__ x, const float* __restrict__ Wg,
    int2* __restrict__ route_e, float2* __restrict__ route_w,
    u16* __restrict__ Xb) {
    int wave = threadIdx.x >> 6, lane = threadIdx.x & 63;
    int n = blockIdx.x * 4 + wave;
    const float* xr = x + (size_t)n * DIM;
    u16* xbr = Xb + (size_t)n * DIM;
    double acc[8] = {0, 0, 0, 0, 0, 0, 0, 0};
#pragma unroll
    for (int it = 0; it < 4; it++) {
        int c = it * 512 + lane * 8;
        float4 a = *(const float4*)(xr + c);
        float4 b = *(const float4*)(xr + c + 4);
        uint4 o;
        o.x = f2bf(a.x) | (f2bf(a.y) << 16);
        o.y = f2bf(a.z) | (f2bf(a.w) << 16);
        o.z = f2bf(b.x) | (f2bf(b.y) << 16);
        o.w = f2bf(b.z) | (f2bf(b.w) << 16);
        *(uint4*)(xbr + c) = o;
        float xv[8] = {a.x, a.y, a.z, a.w, b.x, b.y, b.z, b.w};
        const float4* wp = (const float4*)(Wg + (size_t)c * 8);
#pragma unroll
        for (int j = 0; j < 8; j++) {
            float4 w0 = wp[j * 2], w1 = wp[j * 2 + 1];
            double xd = (double)xv[j];
            acc[0] += xd * (double)w0.x;
            acc[1] += xd * (double)w0.y;
            acc[2] += xd * (double)w0.z;
            acc[3] += xd * (double)w0.w;
            acc[4] += xd * (double)w1.x;
            acc[5] += xd * (double)w1.y;
            acc[6] += xd * (double)w1.z;
            acc[7] += xd * (double)w1.w;
        }
    }
#pragma unroll
    for (int off = 32; off; off >>= 1)
#pragma unroll
        for (int e = 0; e < 8; e++) acc[e] += __shfl_xor(acc[e], off);
    if (lane == 0) {
        float v[8];
#pragma unroll
        for (int e = 0; e < 8; e++) v[e] = (float)acc[e];
        int e0 = 0; float v0 = v[0];
#pragma unroll
        for (int e = 1; e < 8; e++) if (v[e] > v0) { v0 = v[e]; e0 = e; }
        int e1 = -1; float v1 = -1e30f;
#pragma unroll
        for (int e = 0; e < 8; e++) if (e != e0 && v[e] > v1) { v1 = v[e]; e1 = e; }
        float ex = expf(v1 - v0);             // <= 1, stable
        route_e[n] = make_int2(e0, e1);
        route_w[n] = make_float2(1.0f / (1.0f + ex), ex / (1.0f + ex));
    }
}

// ---- hist: per-chunk expert histograms (32 blocks) ---------------------
__global__ __launch_bounds__(256) void k_hist(
    const int2* __restrict__ route_e, int* __restrict__ hist) {
    __shared__ int h[NEXP];
    int c = blockIdx.x, t = threadIdx.x;
    if (t < NEXP) h[t] = 0;
    __syncthreads();
    int2 re = route_e[c * 256 + t];
    atomicAdd(&h[re.x], 1);
    atomicAdd(&h[re.y], 1);
    __syncthreads();
    if (t < NEXP) hist[c * NEXP + t] = h[t];
}

// ---- scan: per-expert exclusive prefix over chunks (nano) --------------
__global__ void k_scan(const int* __restrict__ hist, int* __restrict__ pre,
                       int* __restrict__ cnt) {
    int e = threadIdx.x;
    if (e < NEXP) {
        int run = 0;
        for (int c = 0; c < NCHUNK; c++) { pre[c * NEXP + e] = run; run += hist[c * NEXP + e]; }
        cnt[e] = run;
    }
}

// ---- assign: ballot-ranked slot assignment (32 blocks) -----------------
__global__ __launch_bounds__(256) void k_assign(
    const int2* __restrict__ route_e, const int* __restrict__ pre,
    int4* __restrict__ route_i, int* __restrict__ tok_idx) {
    __shared__ int wc0[4][NEXP], wc1[4][NEXP];
    int c = blockIdx.x, t = threadIdx.x, wave = t >> 6, lane = t & 63;
    int n = c * 256 + t;
    int2 re = route_e[n];
    unsigned long long lt = ((unsigned long long)1 << lane) - 1;
    int r0 = 0, r1 = 0;
#pragma unroll
    for (int e = 0; e < NEXP; e++) {
        unsigned long long m0 = __ballot(re.x == e);
        unsigned long long m1 = __ballot(re.y == e);
        if (lane == 0) { wc0[wave][e] = __popcll(m0); wc1[wave][e] = __popcll(m1); }
        if (re.x == e) r0 = __popcll(m0 & lt);
        if (re.y == e) r1 = __popcll(m1 & lt);
    }
    __syncthreads();
    int h0tot = 0;   // total e0-instances of expert re.y in this chunk
#pragma unroll
    for (int w = 0; w < 4; w++) {
        if (w < wave) { r0 += wc0[w][re.x]; r1 += wc1[w][re.y]; }
        h0tot += wc0[w][re.y];
    }
    int p0 = pre[c * NEXP + re.x] + r0;
    int p1 = pre[c * NEXP + re.y] + h0tot + r1;
    route_i[n] = make_int4(re.x, re.y, p0, p1);
    tok_idx[re.x * N_TOK + p0] = n;
    tok_idx[re.y * N_TOK + p1] = n;
}

// ---- transpose We[e][k][n] fp32 -> Wt[e][n][k] bf16, 4 tiles/block -----
__global__ __launch_bounds__(256) void k_transpose_we(
    const float* __restrict__ We, u16* __restrict__ Wt) {
    __shared__ float t[64][65];
    int e = blockIdx.z, n0 = blockIdx.x * 64, k00 = blockIdx.y * 256;
    int tid = threadIdx.x;
    for (int kt = 0; kt < 4; kt++) {
        int k0 = k00 + kt * 64;
        const float* src = We + ((size_t)e * DIM + k0) * DIM + n0;
        if (kt) __syncthreads();
#pragma unroll
        for (int it = 0; it < 4; it++) {
            int item = it * 256 + tid;
            int r = item >> 4, c4 = (item & 15) * 4;
            float4 v = *(const float4*)(src + (size_t)r * DIM + c4);
            t[r][c4] = v.x; t[r][c4 + 1] = v.y; t[r][c4 + 2] = v.z; t[r][c4 + 3] = v.w;
        }
        __syncthreads();
        u16* dst = Wt + ((size_t)e * DIM + n0) * DIM + k0;
#pragma unroll
        for (int it = 0; it < 2; it++) {
            int item = it * 256 + tid;
            int nl = item >> 3, kc = (item & 7) * 8;
            unsigned m[8];
#pragma unroll
            for (int j = 0; j < 8; j++) m[j] = f2bf(t[kc + j][nl]);
            uint4 o;
            o.x = m[0] | (m[1] << 16); o.y = m[2] | (m[3] << 16);
            o.z = m[4] | (m[5] << 16); o.w = m[6] | (m[7] << 16);
            *(uint4*)(dst + (size_t)nl * DIM + kc) = o;
        }
    }
}

// ---- grouped gather-GEMM, 256x256 tile, BK=64, 8 waves, 2 barriers/tile.
// Grid 1024: bid<512 = full tiles (m-tiles 0..63, 2 clean rounds).
//            bid>=512 = overflow tiles (m-tile>=64) split-K x8: each
//            eighth covers 4 K-tiles, writes raw fp32 partials to Ys
//            (bias added in k_combine). Kills the 3rd dispatch round.
__global__ __launch_bounds__(512, 2) void k_moe_gemm(
    const u16* __restrict__ Xb, const u16* __restrict__ Wt,
    const float* __restrict__ be, const int* __restrict__ cnt,
    const int* __restrict__ tok_idx, u16* __restrict__ Yp,
    float* __restrict__ Ys) {
    extern __shared__ u16 lds[];   // [A0|A1|B0|B1] each 256*64 u16 = 32KB

    int base[NEXP]; int pb = 0;
#pragma unroll
    for (int i = 0; i < NEXP; i++) { base[i] = pb; pb += ((cnt[i] + 255) >> 8) << 8; }

    int bid = blockIdx.x;
    int f, tb, tn;
    float* ysc = nullptr;
    if (bid < NFULL) {
        // XCD-aware bijective swizzle over the 512 full tiles (64 m x 8 n)
        f = (bid & 7) * (NFULL / 8) + (bid >> 3);
        tb = 0; tn = 32;
    } else {
        int i8 = (bid - NFULL) >> 3, k8 = (bid - NFULL) & 7;
        f = NFULL + i8;           // overflow tile id (m-tile 64+, n = f&7)
        tb = k8 * 4; tn = 4;      // 4 K-tiles = 256 K-cols per eighth
        ysc = Ys + ((size_t)i8 * 8 + k8) * 65536;
    }
    int m0 = (f >> 3) << 8, n0 = (f & 7) << 8;
    if (m0 >= pb) return;
    int e = 0;
#pragma unroll
    for (int i = 1; i < NEXP; i++) if (m0 >= base[i]) e = i;

    int tid = threadIdx.x, wave = tid >> 6, lane = tid & 63;
    int q = lane >> 4, mr = lane & 15;
    int wr = (wave >> 2) << 7;   // 0 / 128
    int wc = (wave & 3) << 6;    // 0 / 64 / 128 / 192

    // per-lane pre-swizzled global staging pointers (4 64-row rounds each),
    // pre-offset to this block's K-range start
    const u16* pA[4]; const u16* pB[4];
#pragma unroll
    for (int j = 0; j < 4; j++) {
        int r = j * 64 + wave * 8 + (lane >> 3);
        int swz = ((lane & 7) ^ ((r >> 1) & 7)) << 3;
        int slot = m0 + r - base[e];
        int tok = tok_idx[e * N_TOK + slot] & (N_TOK - 1);   // pad rows masked
        pA[j] = Xb + (size_t)tok * DIM + swz + (tb << 6);
        pB[j] = Wt + ((size_t)e * DIM + n0 + r) * DIM + swz + (tb << 6);
    }

    u16* cA = lds;             u16* nA = lds + 16384;
    u16* cB = lds + 32768;     u16* nB = lds + 49152;
    int dofs = wave << 9;      // wave*8 rows * 64 elems

    f32x4 acc[8][4] = {};

    // ---- prologue: stage tile 0; issue order == steady-state order -----
    gload16(pB[0], cB + 0     + dofs);
    gload16(pB[1], cB + 4096  + dofs);
    gload16(pA[0], cA + 0     + dofs);
    gload16(pA[2], cA + 8192  + dofs);
    gload16(pB[2], cB + 8192  + dofs);
    gload16(pB[3], cB + 12288 + dofs);
    gload16(pA[1], cA + 4096  + dofs);
    gload16(pA[3], cA + 12288 + dofs);
    asm volatile("s_waitcnt vmcnt(2)" ::: "memory");   // A1,A3 stay in flight
    __builtin_amdgcn_s_barrier();
    __builtin_amdgcn_sched_barrier(0);

#pragma unroll 2
    for (int t = 0; t < tn; t++) {
        int koff = (t + 1 < tn ? t + 1 : tn - 1) << 6;   // last iter: harmless restage
        // ======== half 1: B + A-early (acc rows 0..3), stage t+1 ========
        gload16(pB[0] + koff, nB + 0     + dofs);
        gload16(pB[1] + koff, nB + 4096  + dofs);
        gload16(pA[0] + koff, nA + 0     + dofs);
        gload16(pA[2] + koff, nA + 8192  + dofs);
        bf16x8 b[4][2];
#pragma unroll
        for (int j = 0; j < 4; j++) {
            int R = wc + j * 16 + mr, sw = (R >> 1) & 7;
            b[j][0] = *(const bf16x8*)(cB + (R << 6) + (((0 + q) ^ sw) << 3));
            b[j][1] = *(const bf16x8*)(cB + (R << 6) + (((4 + q) ^ sw) << 3));
        }
        {
            bf16x8 a[2][2];
#pragma unroll
            for (int i2 = 0; i2 < 2; i2++) {
                int R = wr + i2 * 16 + mr, sw = (R >> 1) & 7;
                a[i2][0] = *(const bf16x8*)(cA + (R << 6) + (((0 + q) ^ sw) << 3));
                a[i2][1] = *(const bf16x8*)(cA + (R << 6) + (((4 + q) ^ sw) << 3));
            }
            __builtin_amdgcn_s_setprio(1);
#pragma unroll
            for (int kh = 0; kh < 2; kh++)
#pragma unroll
                for (int i2 = 0; i2 < 2; i2++)
#pragma unroll
                    for (int j = 0; j < 4; j++)
                        acc[i2][j] = __builtin_amdgcn_mfma_f32_16x16x32_bf16(
                            a[i2][kh], b[j][kh], acc[i2][j], 0, 0, 0);
            __builtin_amdgcn_s_setprio(0);
        }
        gload16(pB[2] + koff, nB + 8192  + dofs);
        gload16(pB[3] + koff, nB + 12288 + dofs);
        gload16(pA[1] + koff, nA + 4096  + dofs);
        gload16(pA[3] + koff, nA + 12288 + dofs);
        {
            bf16x8 a[2][2];
#pragma unroll
            for (int i2 = 0; i2 < 2; i2++) {
                int R = wr + 32 + i2 * 16 + mr, sw = (R >> 1) & 7;
                a[i2][0] = *(const bf16x8*)(cA + (R << 6) + (((0 + q) ^ sw) << 3));
                a[i2][1] = *(const bf16x8*)(cA + (R << 6) + (((4 + q) ^ sw) << 3));
            }
            __builtin_amdgcn_s_setprio(1);
#pragma unroll
            for (int kh = 0; kh < 2; kh++)
#pragma unroll
                for (int i2 = 0; i2 < 2; i2++)
#pragma unroll
                    for (int j = 0; j < 4; j++)
                        acc[2 + i2][j] = __builtin_amdgcn_mfma_f32_16x16x32_bf16(
                            a[i2][kh], b[j][kh], acc[2 + i2][j], 0, 0, 0);
            __builtin_amdgcn_s_setprio(0);
        }
        // ledger: carried-in 2 (A1,A3 of t) + 8 issued => drain the 2 oldest
        asm volatile("s_waitcnt vmcnt(8)" ::: "memory");
        __builtin_amdgcn_sched_barrier(0);
        __builtin_amdgcn_s_barrier();            // Bmid: A-late of t valid
        __builtin_amdgcn_sched_barrier(0);
        // ======== half 2: A-late (acc rows 4..7) ========
        {
            bf16x8 a[2][2];
#pragma unroll
            for (int i2 = 0; i2 < 2; i2++) {
                int R = wr + 64 + i2 * 16 + mr, sw = (R >> 1) & 7;
                a[i2][0] = *(const bf16x8*)(cA + (R << 6) + (((0 + q) ^ sw) << 3));
                a[i2][1] = *(const bf16x8*)(cA + (R << 6) + (((4 + q) ^ sw) << 3));
            }
            __builtin_amdgcn_s_setprio(1);
#pragma unroll
            for (int kh = 0; kh < 2; kh++)
#pragma unroll
                for (int i2 = 0; i2 < 2; i2++)
#pragma unroll
                    for (int j = 0; j < 4; j++)
                        acc[4 + i2][j] = __builtin_amdgcn_mfma_f32_16x16x32_bf16(
                            a[i2][kh], b[j][kh], acc[4 + i2][j], 0, 0, 0);
            __builtin_amdgcn_s_setprio(0);
        }
        {
            bf16x8 a[2][2];
#pragma unroll
            for (int i2 = 0; i2 < 2; i2++) {
                int R = wr + 96 + i2 * 16 + mr, sw = (R >> 1) & 7;
                a[i2][0] = *(const bf16x8*)(cA + (R << 6) + (((0 + q) ^ sw) << 3));
                a[i2][1] = *(const bf16x8*)(cA + (R << 6) + (((4 + q) ^ sw) << 3));
            }
            __builtin_amdgcn_s_setprio(1);
#pragma unroll
            for (int kh = 0; kh < 2; kh++)
#pragma unroll
                for (int i2 = 0; i2 < 2; i2++)
#pragma unroll
                    for (int j = 0; j < 4; j++)
                        acc[6 + i2][j] = __builtin_amdgcn_mfma_f32_16x16x32_bf16(
                            a[i2][kh], b[j][kh], acc[6 + i2][j], 0, 0, 0);
            __builtin_amdgcn_s_setprio(0);
        }
        // keep next tile's A1,A3 in flight across the tile barrier
        asm volatile("s_waitcnt vmcnt(2)" ::: "memory");
        __builtin_amdgcn_sched_barrier(0);
        __builtin_amdgcn_s_barrier();            // Bend: B,A-early of t+1 valid
        __builtin_amdgcn_sched_barrier(0);
        u16* tp;
        tp = cA; cA = nA; nA = tp;
        tp = cB; cB = nB; nB = tp;
    }
    asm volatile("s_waitcnt vmcnt(0)" ::: "memory");

    // ---- epilogue ------------------------------------------------------
    if (bid < NFULL) {
        float bev[4];
#pragma unroll
        for (int j = 0; j < 4; j++) bev[j] = be[e * DIM + n0 + wc + j * 16 + mr];
#pragma unroll
        for (int i = 0; i < 8; i++) {
#pragma unroll
            for (int r = 0; r < 4; r++) {
                int row = wr + i * 16 + q * 4 + r;
                u16* yrow = Yp + (size_t)(m0 + row) * DIM + n0 + wc + mr;
#pragma unroll
                for (int j = 0; j < 4; j++)
                    yrow[j * 16] = (u16)f2bf(acc[i][j][r] + bev[j]);
            }
        }
    } else {
        // raw fp32 partials, chunk layout [256 rows][256 cols]; no bias
#pragma unroll
        for (int i = 0; i < 8; i++) {
#pragma unroll
            for (int r = 0; r < 4; r++) {
                int row = wr + i * 16 + q * 4 + r;
                float* yo = ysc + (size_t)row * 256 + wc + mr;
#pragma unroll
                for (int j = 0; j < 4; j++)
                    yo[j * 16] = acc[i][j][r];
            }
        }
    }
}

// ---- combine: out[n] = w0*(Y[r0]) + w1*(Y[r1]); tail rows (>=16384)
// are summed from the 8 fp32 split-K chunks + bias here. ----------------
__global__ __launch_bounds__(256) void k_combine(
    const u16* __restrict__ Yp, const float* __restrict__ Ys,
    const float* __restrict__ be, const int* __restrict__ cnt,
    const int4* __restrict__ route_i, const float2* __restrict__ route_w,
    float* __restrict__ out) {
    int base[NEXP]; int pb = 0;
#pragma unroll
    for (int i = 0; i < NEXP; i++) { base[i] = pb; pb += ((cnt[i] + 255) >> 8) << 8; }
    int n = blockIdx.x, tid = threadIdx.x;
    int4 ri = route_i[n]; float2 w = route_w[n];
    size_t r0 = (size_t)base[ri.x] + ri.z;
    size_t r1 = (size_t)base[ri.y] + ri.w;
    int c0 = tid * 8;
    float y0[8], y1[8];
#pragma unroll
    for (int side = 0; side < 2; side++) {
        size_t r = side ? r1 : r0;
        int ex = side ? ri.y : ri.x;
        float* y = side ? y1 : y0;
        if (r < (size_t)(NFULL * 32)) {           // 16384: full-tile region
            uint4 ya = ((const uint4*)(Yp + r * DIM))[tid];
            unsigned v[4] = {ya.x, ya.y, ya.z, ya.w};
#pragma unroll
            for (int k = 0; k < 4; k++) {
                y[2 * k]     = __uint_as_float(v[k] << 16);
                y[2 * k + 1] = __uint_as_float(v[k] & 0xffff0000u);
            }
        } else {                                  // split-K tail region
            int i8 = ((int)(r >> 8) - 64) * 8 + (c0 >> 8);
            const float* p = Ys + (size_t)i8 * 8 * 65536
                             + (size_t)((int)(r & 255) * 256 + (c0 & 255));
            float s[8] = {0, 0, 0, 0, 0, 0, 0, 0};
#pragma unroll
            for (int k8 = 0; k8 < 8; k8++) {
                float4 u0 = *(const float4*)(p + (size_t)k8 * 65536);
                float4 u1 = *(const float4*)(p + (size_t)k8 * 65536 + 4);
                s[0] += u0.x; s[1] += u0.y; s[2] += u0.z; s[3] += u0.w;
                s[4] += u1.x; s[5] += u1.y; s[6] += u1.z; s[7] += u1.w;
            }
#pragma unroll
            for (int k = 0; k < 8; k++) y[k] = s[k] + be[ex * DIM + c0 + k];
        }
    }
    float4 o0, o1;
    o0.x = w.x * y0[0] + w.y * y1[0];
    o0.y = w.x * y0[1] + w.y * y1[1];
    o0.z = w.x * y0[2] + w.y * y1[2];
    o0.w = w.x * y0[3] + w.y * y1[3];
    o1.x = w.x * y0[4] + w.y * y1[4];
    o1.y = w.x * y0[5] + w.y * y1[5];
    o1.z = w.x * y0[6] + w.y * y1[6];
    o1.w = w.x * y0[7] + w.y * y1[7];
    float4* op = (float4*)(out + (size_t)n * DIM) + tid * 2;
    op[0] = o0; op[1] = o1;
}

extern "C" void kernel_launch(void* const* d_in, const int* in_sizes, int n_in,
                              void* d_out, int out_size, void* d_ws, size_t ws_size,
                              hipStream_t stream) {
    const float* x  = (const float*)d_in[0];   // [N, D]
    const float* Wg = (const float*)d_in[1];   // [D, E]
    const float* We = (const float*)d_in[2];   // [E, D, D]
    const float* be = (const float*)d_in[3];   // [E, D]
    float* out = (float*)d_out;                // [N, D] fp32
    char* ws = (char*)d_ws;
    int*    cnt     = (int*)(ws + OFF_CNT);
    int*    hist    = (int*)(ws + OFF_HIST);
    int*    pre     = (int*)(ws + OFF_PRE);
    int2*   route_e = (int2*)(ws + OFF_RE);
    int4*   route_i = (int4*)(ws + OFF_RI);
    float2* route_w = (float2*)(ws + OFF_RW);
    int*    tok_idx = (int*)(ws + OFF_TIDX);
    u16*    Xb      = (u16*)(ws + OFF_XB);
    u16*    Wt      = (u16*)(ws + OFF_WT);
    u16*    Yp      = (u16*)(ws + OFF_YP);
    float*  Ys      = (float*)(ws + OFF_YS);

    static int g_attr_done = 0;
    if (!g_attr_done) {
        (void)hipFuncSetAttribute((const void*)k_moe_gemm,
                                  hipFuncAttributeMaxDynamicSharedMemorySize,
                                  131072);
        g_attr_done = 1;
    }

    k_gate<<<N_TOK / 4, 256, 0, stream>>>(x, Wg, route_e, route_w, Xb);
    k_hist<<<NCHUNK, 256, 0, stream>>>(route_e, hist);
    k_scan<<<1, 64, 0, stream>>>(hist, pre, cnt);
    k_assign<<<NCHUNK, 256, 0, stream>>>(route_e, pre, route_i, tok_idx);
    k_transpose_we<<<dim3(DIM / 64, DIM / 256, NEXP), 256, 0, stream>>>(We, Wt);
    k_moe_gemm<<<dim3(NFULL + NTAIL * 8), 512, 131072, stream>>>(
        Xb, Wt, be, cnt, tok_idx, Yp, Ys);
    k_combine<<<N_TOK, 256, 0, stream>>>(Yp, Ys, be, cnt, route_i, route_w, out);
}